// Round 1
// baseline (3579.777 us; speedup 1.0000x reference)
//
#include <hip/hip_runtime.h>
#include <math.h>

// S4DConv: B=8, L=2048, H=512, N=64, CH=1
// Pipeline (must match np reference exactly in structure):
//   k[h,t]   = 2 Re( sum_n Cs[h,n] z[h,n]^t ),  z = exp(dt*w), Cs = C*(z-1)/w
//   K_f[h,j] = DFT_4095(k)[j],  j=0..2047      (closed-form geometric series)
//   U_f[b,h,j] = DFT_4095(u_row)[j]
//   y[b,h,t] = irfft_4096( K_f * U_f  padded with one zero bin )[t], t<2048
//   out[b,t,0,h] = y + D[h]*u[b,t,h]

namespace {
constexpr int cB = 8;
constexpr int cL = 2048;
constexpr int cH = 512;
constexpr int cN = 64;
constexpr int M1 = 4095;   // forward DFT length (2l-1)
constexpr int M2 = 4096;   // inverse length (2l)
constexpr int NB = 2048;   // number of rfft bins used

// ws layout (float offsets)
constexpr int WS_MODES = 0;                 // [H][N][6]: Cs_re,Cs_im,z_re,z_im,zl_re,zl_im
constexpr int WS_JTAB  = cH * cN * 6;       // [NB][4]: q_re,q_im,ql_re,ql_im
constexpr int WS_KF    = WS_JTAB + NB * 4;  // [H][NB][2] scaled K_f
}

__global__ __launch_bounds__(256) void k_precomp(
    const float* __restrict__ w_re, const float* __restrict__ w_im,
    const float* __restrict__ C_re, const float* __restrict__ C_im,
    const float* __restrict__ dt, float* __restrict__ W)
{
    int idx = blockIdx.x * 256 + threadIdx.x;
    if (idx < cH * cN) {
        int h = idx / cN;
        double dtv = dt[h];
        double wr = w_re[idx], wi = w_im[idx];
        double ar = wr * dtv, ai = wi * dtv;          // dtA
        double er = exp(ar);
        double zs, zc; sincos(ai, &zs, &zc);
        double zr = er * zc, zi = er * zs;            // z = exp(dtA)
        double el = exp(ar * (double)cL);
        double ph = fmod(ai * (double)cL, 2.0 * M_PI);
        double ls, lc; sincos(ph, &ls, &lc);
        double zlr = el * lc, zli = el * ls;          // z^L
        // Cs = C * (z-1)/w
        double nr = zr - 1.0, ni = zi;
        double inv = 1.0 / (wr * wr + wi * wi);
        double gr = (nr * wr + ni * wi) * inv;
        double gi = (ni * wr - nr * wi) * inv;
        double cr = C_re[idx], ci = C_im[idx];
        double csr = cr * gr - ci * gi, csi = cr * gi + ci * gr;
        float* m = W + WS_MODES + idx * 6;
        m[0] = (float)csr; m[1] = (float)csi;
        m[2] = (float)zr;  m[3] = (float)zi;
        m[4] = (float)zlr; m[5] = (float)zli;
    } else if (idx < cH * cN + NB) {
        int j = idx - cH * cN;
        double s, c;  sincos(-2.0 * M_PI * (double)j / (double)M1, &s, &c);
        long p = ((long)j * (long)cL) % M1;           // exact phase of q_j^L
        double sl, cl2; sincos(-2.0 * M_PI * (double)p / (double)M1, &sl, &cl2);
        float* t = W + WS_JTAB + j * 4;
        t[0] = (float)c;   t[1] = (float)s;
        t[2] = (float)cl2; t[3] = (float)sl;
    }
}

// K_f[h,j] = sum_{t<L} k[h,t] q_j^t
//          = Cs (1 - z^L q^L)/(1 - z q) + conj(Cs) (1 - conj(z)^L q^L)/(1 - conj(z) q)
__global__ __launch_bounds__(256) void k_kf(float* W)
{
    __shared__ float md[cN * 6];
    int h = blockIdx.x >> 3;
    int j = ((blockIdx.x & 7) << 8) + threadIdx.x;
    for (int i = threadIdx.x; i < cN * 6; i += 256)
        md[i] = W[WS_MODES + h * cN * 6 + i];
    __syncthreads();
    const float4 jt = *reinterpret_cast<const float4*>(W + WS_JTAB + j * 4);
    float qr = jt.x, qi = jt.y, qlr = jt.z, qli = jt.w;
    float accr = 0.f, acci = 0.f;
#pragma unroll 4
    for (int n = 0; n < cN; ++n) {
        float csr = md[n*6+0], csi = md[n*6+1];
        float zr  = md[n*6+2], zi  = md[n*6+3];
        float zlr = md[n*6+4], zli = md[n*6+5];
        // term 1
        float dr = 1.f - (zr * qr - zi * qi);
        float di = -(zr * qi + zi * qr);
        float nr = 1.f - (zlr * qlr - zli * qli);
        float ni = -(zlr * qli + zli * qlr);
        float inv = 1.f / (dr * dr + di * di);
        float gr = (nr * dr + ni * di) * inv;
        float gi = (ni * dr - nr * di) * inv;
        accr += csr * gr - csi * gi;
        acci += csr * gi + csi * gr;
        // term 2 (z, z^L conjugated; Cs conjugated)
        dr = 1.f - (zr * qr + zi * qi);
        di = -(zr * qi - zi * qr);
        nr = 1.f - (zlr * qlr + zli * qli);
        ni = -(zlr * qli - zli * qlr);
        inv = 1.f / (dr * dr + di * di);
        gr = (nr * dr + ni * di) * inv;
        gi = (ni * dr - nr * di) * inv;
        accr += csr * gr + csi * gi;
        acci += csr * gi - csi * gr;
    }
    // fold irfft scale: (j==0 ? 1 : 2)/4096
    float scale = (j == 0 ? 1.0f : 2.0f) / (float)M2;
    *reinterpret_cast<float2*>(W + WS_KF + ((h << 11) + j) * 2) =
        make_float2(accr * scale, acci * scale);
}

__global__ __launch_bounds__(256) void k_main(
    const float* __restrict__ u, const float* __restrict__ Dp,
    const float* __restrict__ W, float* __restrict__ out)
{
    __shared__ float u_s[cL];
    __shared__ float Yr[NB];
    __shared__ float Yi[NB];
    int b = blockIdx.x >> 9;
    int h = blockIdx.x & 511;
    int tid = threadIdx.x;

    // stage u row (strided gather; consecutive blocks share cache lines via h)
    for (int t = tid; t < cL; t += 256)
        u_s[t] = u[((size_t)b * cL + t) * cH + h];
    __syncthreads();

    // ---- forward DFT: U_f[j] = sum_t u[t] e^{-2pi i j t / 4095} ----
    float pr[8], pim[8], sr[8], si[8], Ur[8], Ui[8];
#pragma unroll
    for (int k = 0; k < 8; ++k) {
        int j = tid + (k << 8);
        float ang = (-2.0f * (float)M_PI / (float)M1) * (float)j;
        sincosf(ang, &si[k], &sr[k]);   // per-bin rotation step
        Ur[k] = 0.f; Ui[k] = 0.f;
    }
    for (int t0 = 0; t0 < cL; t0 += 256) {
        // resync phasor exactly: q_j^{t0}, phase from integer (j*t0 mod 4095)
#pragma unroll
        for (int k = 0; k < 8; ++k) {
            int j = tid + (k << 8);
            int p = (j * t0) % M1;
            float ang = (-2.0f * (float)M_PI / (float)M1) * (float)p;
            sincosf(ang, &pim[k], &pr[k]);
        }
        for (int t = t0; t < t0 + 256; ++t) {
            float ut = u_s[t];
#pragma unroll
            for (int k = 0; k < 8; ++k) {
                Ur[k] = fmaf(ut, pr[k], Ur[k]);
                Ui[k] = fmaf(ut, pim[k], Ui[k]);
                float tr = pr[k] * sr[k] - pim[k] * si[k];
                pim[k]   = pr[k] * si[k] + pim[k] * sr[k];
                pr[k] = tr;
            }
        }
    }
    // Y = K_f * U_f (K_f pre-scaled), to LDS
#pragma unroll
    for (int k = 0; k < 8; ++k) {
        int j = tid + (k << 8);
        float2 kf = *reinterpret_cast<const float2*>(W + WS_KF + (((size_t)h << 11) + j) * 2);
        Yr[j] = Ur[k] * kf.x - Ui[k] * kf.y;
        Yi[j] = Ur[k] * kf.y + Ui[k] * kf.x;
    }
    __syncthreads();

    // ---- inverse: y[t] = sum_j Yr[j] cos(2pi j t/4096) - Yi[j] sin(2pi j t/4096) ----
    float cr[8], ci[8], str_[8], sti[8], y[8];
#pragma unroll
    for (int k = 0; k < 8; ++k) {
        int t = tid + (k << 8);
        float ang = (2.0f * (float)M_PI / (float)M2) * (float)t;
        sincosf(ang, &sti[k], &str_[k]);  // per-t rotation step
        y[k] = 0.f;
    }
    for (int j0 = 0; j0 < NB; j0 += 256) {
#pragma unroll
        for (int k = 0; k < 8; ++k) {
            int t = tid + (k << 8);
            int p = (t * j0) & (M2 - 1);
            float ang = (2.0f * (float)M_PI / (float)M2) * (float)p;
            sincosf(ang, &ci[k], &cr[k]);
        }
        for (int j = j0; j < j0 + 256; ++j) {
            float yr = Yr[j], yi = Yi[j];
#pragma unroll
            for (int k = 0; k < 8; ++k) {
                y[k] = fmaf(yr, cr[k], y[k]);
                y[k] = fmaf(-yi, ci[k], y[k]);
                float tr = cr[k] * str_[k] - ci[k] * sti[k];
                ci[k]    = cr[k] * sti[k] + ci[k] * str_[k];
                cr[k] = tr;
            }
        }
    }

    // ---- skip + store: out[b, t, 0, h] ----
    float dv = Dp[h];
#pragma unroll
    for (int k = 0; k < 8; ++k) {
        int t = tid + (k << 8);
        out[((size_t)b * cL + t) * cH + h] = y[k] + dv * u_s[t];
    }
}

extern "C" void kernel_launch(void* const* d_in, const int* in_sizes, int n_in,
                              void* d_out, int out_size, void* d_ws, size_t ws_size,
                              hipStream_t stream) {
    const float* u    = (const float*)d_in[0];
    const float* w_re = (const float*)d_in[1];
    const float* w_im = (const float*)d_in[2];
    const float* C_re = (const float*)d_in[3];
    const float* C_im = (const float*)d_in[4];
    const float* Dp   = (const float*)d_in[5];
    const float* dt   = (const float*)d_in[6];
    float* out = (float*)d_out;
    float* W   = (float*)d_ws;

    int pre_threads = cH * cN + NB;
    hipLaunchKernelGGL(k_precomp, dim3((pre_threads + 255) / 256), dim3(256), 0, stream,
                       w_re, w_im, C_re, C_im, dt, W);
    hipLaunchKernelGGL(k_kf, dim3(cH * (NB / 256)), dim3(256), 0, stream, W);
    hipLaunchKernelGGL(k_main, dim3(cB * cH), dim3(256), 0, stream, u, Dp, W, out);
}

// Round 2
// 353.972 us; speedup vs baseline: 10.1132x; 10.1132x over previous
//
#include <hip/hip_runtime.h>
#include <hip/hip_bf16.h>
#include <math.h>

// S4DConv via MFMA: B=8, L=2048, H=512, N=64, CH=1
//   K_f[h,j]   = DFT_4095(k)[j] closed-form (fp32, unchanged from r1)
//   U^T[bh,j]  = bf16 GEMM: Au[bh,t] x {T1c,T1s}[j,t]   (dual accumulator)
//   Ys[bh,:]   = K_f * U (complex, fp32) -> bf16, cols 0..2047=Ysr, 2048..=-Ysi
//   y^T[bh,t]  = bf16 GEMM: Ys[bh,k] x T2[t,k]  (K=4096: cos|sin halves)
//   out[b,t,h] = y + D[h]*u   (fp32 skip, exact)

namespace {
constexpr int cB = 8;
constexpr int cL = 2048;
constexpr int cH = 512;
constexpr int cN = 64;
constexpr int M1 = 4095;
constexpr int M2 = 4096;
constexpr int NB = 2048;
constexpr int BH = cB * cH;   // 4096

// float-offset regions in ws
constexpr size_t WS_MODES = 0;                       // [H][N][6]
constexpr size_t WS_JTAB  = (size_t)cH * cN * 6;     // [NB][4]
constexpr size_t WS_KF    = WS_JTAB + (size_t)NB * 4;// [H][NB][2] (c_j folded)
// short-offset regions (ws viewed as short*), 16B aligned
constexpr size_t S_BF  = 2 * (WS_KF + (size_t)cH * NB * 2);
constexpr size_t S_T1C = S_BF;                          // [NB][2048]
constexpr size_t S_T1S = S_T1C + (size_t)NB * 2048;     // [NB][2048]
constexpr size_t S_T2  = S_T1S + (size_t)NB * 2048;     // [2048][4096]
constexpr size_t S_AU  = S_T2  + (size_t)2048 * 4096;   // [BH][2048]
constexpr size_t S_YS  = S_AU  + (size_t)BH * 2048;     // [BH][4096]
}

typedef __attribute__((ext_vector_type(8))) short short8;
typedef __attribute__((ext_vector_type(4))) float f32x4;

static __device__ inline short f2bf(float x) {
    __hip_bfloat16 h = __float2bfloat16(x);
    return *reinterpret_cast<short*>(&h);
}

__global__ __launch_bounds__(256) void k_precomp(
    const float* __restrict__ w_re, const float* __restrict__ w_im,
    const float* __restrict__ C_re, const float* __restrict__ C_im,
    const float* __restrict__ dt, float* __restrict__ W)
{
    int idx = blockIdx.x * 256 + threadIdx.x;
    if (idx < cH * cN) {
        int h = idx / cN;
        double dtv = dt[h];
        double wr = w_re[idx], wi = w_im[idx];
        double ar = wr * dtv, ai = wi * dtv;
        double er = exp(ar);
        double zs, zc; sincos(ai, &zs, &zc);
        double zr = er * zc, zi = er * zs;
        double el = exp(ar * (double)cL);
        double ph = fmod(ai * (double)cL, 2.0 * M_PI);
        double ls, lc; sincos(ph, &ls, &lc);
        double zlr = el * lc, zli = el * ls;
        double nr = zr - 1.0, ni = zi;
        double inv = 1.0 / (wr * wr + wi * wi);
        double gr = (nr * wr + ni * wi) * inv;
        double gi = (ni * wr - nr * wi) * inv;
        double cr = C_re[idx], ci = C_im[idx];
        double csr = cr * gr - ci * gi, csi = cr * gi + ci * gr;
        float* m = W + WS_MODES + (size_t)idx * 6;
        m[0] = (float)csr; m[1] = (float)csi;
        m[2] = (float)zr;  m[3] = (float)zi;
        m[4] = (float)zlr; m[5] = (float)zli;
    } else if (idx < cH * cN + NB) {
        int j = idx - cH * cN;
        double s, c;  sincos(-2.0 * M_PI * (double)j / (double)M1, &s, &c);
        long p = ((long)j * (long)cL) % M1;
        double sl, cl2; sincos(-2.0 * M_PI * (double)p / (double)M1, &sl, &cl2);
        float* t = W + WS_JTAB + (size_t)j * 4;
        t[0] = (float)c;   t[1] = (float)s;
        t[2] = (float)cl2; t[3] = (float)sl;
    }
}

__global__ __launch_bounds__(256) void k_kf(float* W)
{
    __shared__ float md[cN * 6];
    int h = blockIdx.x >> 3;
    int j = ((blockIdx.x & 7) << 8) + threadIdx.x;
    for (int i = threadIdx.x; i < cN * 6; i += 256)
        md[i] = W[WS_MODES + (size_t)h * cN * 6 + i];
    __syncthreads();
    const float4 jt = *reinterpret_cast<const float4*>(W + WS_JTAB + (size_t)j * 4);
    float qr = jt.x, qi = jt.y, qlr = jt.z, qli = jt.w;
    float accr = 0.f, acci = 0.f;
#pragma unroll 4
    for (int n = 0; n < cN; ++n) {
        float csr = md[n*6+0], csi = md[n*6+1];
        float zr  = md[n*6+2], zi  = md[n*6+3];
        float zlr = md[n*6+4], zli = md[n*6+5];
        float dr = 1.f - (zr * qr - zi * qi);
        float di = -(zr * qi + zi * qr);
        float nr = 1.f - (zlr * qlr - zli * qli);
        float ni = -(zlr * qli + zli * qlr);
        float inv = 1.f / (dr * dr + di * di);
        float gr = (nr * dr + ni * di) * inv;
        float gi = (ni * dr - nr * di) * inv;
        accr += csr * gr - csi * gi;
        acci += csr * gi + csi * gr;
        dr = 1.f - (zr * qr + zi * qi);
        di = -(zr * qi - zi * qr);
        nr = 1.f - (zlr * qlr + zli * qli);
        ni = -(zlr * qli - zli * qlr);
        inv = 1.f / (dr * dr + di * di);
        gr = (nr * dr + ni * di) * inv;
        gi = (ni * dr - nr * di) * inv;
        accr += csr * gr + csi * gi;
        acci += csr * gi - csi * gr;
    }
    float scale = (j == 0 ? 1.0f : 2.0f) / (float)M2;
    *reinterpret_cast<float2*>(W + WS_KF + ((size_t)(h << 11) + j) * 2) =
        make_float2(accr * scale, acci * scale);
}

// T1c[j][t]=cos(2pi*jt/4095), T1s[j][t]=sin(2pi*jt/4095)
__global__ __launch_bounds__(256) void k_tab1(short* __restrict__ Wb)
{
    int g = blockIdx.x * 256 + threadIdx.x;   // 2048*2048
    int j = g >> 11, t = g & 2047;
    int p = (j * t) % M1;
    float s, c;
    sincosf((6.283185307179586f / (float)M1) * (float)p, &s, &c);
    Wb[S_T1C + (size_t)g] = f2bf(c);
    Wb[S_T1S + (size_t)g] = f2bf(s);
}

// T2[t][j]=cos(2pi*tj/4096), T2[t][2048+j]=sin(2pi*tj/4096)
__global__ __launch_bounds__(256) void k_tab2(short* __restrict__ Wb)
{
    int g = blockIdx.x * 256 + threadIdx.x;   // 2048*2048
    int t = g >> 11, j = g & 2047;
    int p = (t * j) & (M2 - 1);
    float s, c;
    sincosf((6.283185307179586f / (float)M2) * (float)p, &s, &c);
    Wb[S_T2 + (size_t)t * 4096 + j]        = f2bf(c);
    Wb[S_T2 + (size_t)t * 4096 + 2048 + j] = f2bf(s);
}

// Au[b*512+h][t] = bf16(u[b][t][h])
__global__ __launch_bounds__(256) void k_trans(const float* __restrict__ u,
                                               short* __restrict__ Wb)
{
    __shared__ float tile[64][65];
    int t0 = blockIdx.x * 64;
    int h0 = blockIdx.y * 64;
    int b  = blockIdx.z;
    int cx = threadIdx.x & 63, r0 = threadIdx.x >> 6;
#pragma unroll
    for (int i = 0; i < 16; ++i) {
        int row = r0 + i * 4;
        tile[row][cx] = u[((size_t)b * cL + t0 + row) * cH + h0 + cx];
    }
    __syncthreads();
    short* Au = Wb + S_AU;
#pragma unroll
    for (int i = 0; i < 16; ++i) {
        int hrow = r0 + i * 4;
        Au[(size_t)(b * cH + h0 + hrow) * 2048 + t0 + cx] = f2bf(tile[cx][hrow]);
    }
}

// forward dual GEMM: Ur/Ui over [bh=4096][j=2048], K=2048; epilogue: x K_f -> Ys bf16
__global__ __launch_bounds__(256, 2) void k_fwd(const float* __restrict__ Wf,
                                                short* __restrict__ Wb)
{
    __shared__ short As[128][40], Bc[128][40], Bs[128][40];
    const short* Au  = Wb + S_AU;
    const short* T1c = Wb + S_T1C;
    const short* T1s = Wb + S_T1S;
    short* Ys = Wb + S_YS;
    const int tid = threadIdx.x;
    const int m0 = blockIdx.y * 128, n0 = blockIdx.x * 128;
    const int wave = tid >> 6, lane = tid & 63;
    const int wr = wave >> 1, wc = wave & 1;
    const int lm = lane & 15, lk = lane >> 4;
    const int r0 = tid >> 2, cb = tid & 3;

    f32x4 accC[4][4] = {}, accS[4][4] = {};

    for (int k0 = 0; k0 < 2048; k0 += 32) {
        __syncthreads();
#pragma unroll
        for (int it = 0; it < 2; ++it) {
            int row = r0 + it * 64;
            *(short8*)&As[row][cb*8] = *(const short8*)&Au [(size_t)(m0+row)*2048 + k0 + cb*8];
            *(short8*)&Bc[row][cb*8] = *(const short8*)&T1c[(size_t)(n0+row)*2048 + k0 + cb*8];
            *(short8*)&Bs[row][cb*8] = *(const short8*)&T1s[(size_t)(n0+row)*2048 + k0 + cb*8];
        }
        __syncthreads();
        short8 a[4];
#pragma unroll
        for (int mi = 0; mi < 4; ++mi)
            a[mi] = *(const short8*)&As[wr*64 + mi*16 + lm][lk*8];
#pragma unroll
        for (int ni = 0; ni < 4; ++ni) {
            short8 bc = *(const short8*)&Bc[wc*64 + ni*16 + lm][lk*8];
            short8 bs = *(const short8*)&Bs[wc*64 + ni*16 + lm][lk*8];
#pragma unroll
            for (int mi = 0; mi < 4; ++mi) {
                accC[mi][ni] = __builtin_amdgcn_mfma_f32_16x16x32_bf16(a[mi], bc, accC[mi][ni], 0, 0, 0);
                accS[mi][ni] = __builtin_amdgcn_mfma_f32_16x16x32_bf16(a[mi], bs, accS[mi][ni], 0, 0, 0);
            }
        }
    }

    const float* KF = Wf + WS_KF;
#pragma unroll
    for (int mi = 0; mi < 4; ++mi)
#pragma unroll
    for (int ni = 0; ni < 4; ++ni)
#pragma unroll
    for (int r = 0; r < 4; ++r) {
        int bh = m0 + wr*64 + mi*16 + lk*4 + r;
        int j  = n0 + wc*64 + ni*16 + lm;
        int h  = bh & (cH - 1);
        float2 kf = *(const float2*)&KF[((size_t)h * NB + j) * 2];
        float ur = accC[mi][ni][r], ui = -accS[mi][ni][r];
        float ysr = kf.x * ur - kf.y * ui;
        float ysi = kf.x * ui + kf.y * ur;
        Ys[(size_t)bh * 4096 + j]        = f2bf(ysr);
        Ys[(size_t)bh * 4096 + 2048 + j] = f2bf(-ysi);
    }
}

// inverse GEMM: y[bh][t], K=4096 over Ys x T2; epilogue adds D*u, writes out
__global__ __launch_bounds__(256, 2) void k_inv(const float* __restrict__ u,
                                                const float* __restrict__ Dp,
                                                const short* __restrict__ Wb,
                                                float* __restrict__ out)
{
    __shared__ short As[128][40], Bt[128][40];
    const short* Ys = Wb + S_YS;
    const short* T2 = Wb + S_T2;
    const int tid = threadIdx.x;
    const int m0 = blockIdx.y * 128, n0 = blockIdx.x * 128;
    const int wave = tid >> 6, lane = tid & 63;
    const int wr = wave >> 1, wc = wave & 1;
    const int lm = lane & 15, lk = lane >> 4;
    const int r0 = tid >> 2, cb = tid & 3;

    f32x4 acc[4][4] = {};

    for (int k0 = 0; k0 < 4096; k0 += 32) {
        __syncthreads();
#pragma unroll
        for (int it = 0; it < 2; ++it) {
            int row = r0 + it * 64;
            *(short8*)&As[row][cb*8] = *(const short8*)&Ys[(size_t)(m0+row)*4096 + k0 + cb*8];
            *(short8*)&Bt[row][cb*8] = *(const short8*)&T2[(size_t)(n0+row)*4096 + k0 + cb*8];
        }
        __syncthreads();
        short8 a[4];
#pragma unroll
        for (int mi = 0; mi < 4; ++mi)
            a[mi] = *(const short8*)&As[wr*64 + mi*16 + lm][lk*8];
#pragma unroll
        for (int ni = 0; ni < 4; ++ni) {
            short8 b = *(const short8*)&Bt[wc*64 + ni*16 + lm][lk*8];
#pragma unroll
            for (int mi = 0; mi < 4; ++mi)
                acc[mi][ni] = __builtin_amdgcn_mfma_f32_16x16x32_bf16(a[mi], b, acc[mi][ni], 0, 0, 0);
        }
    }

#pragma unroll
    for (int mi = 0; mi < 4; ++mi)
#pragma unroll
    for (int ni = 0; ni < 4; ++ni)
#pragma unroll
    for (int r = 0; r < 4; ++r) {
        int bh = m0 + wr*64 + mi*16 + lk*4 + r;
        int t  = n0 + wc*64 + ni*16 + lm;
        int b  = bh >> 9, h = bh & (cH - 1);
        size_t idx = ((size_t)b * cL + t) * cH + h;
        out[idx] = acc[mi][ni][r] + Dp[h] * u[idx];
    }
}

extern "C" void kernel_launch(void* const* d_in, const int* in_sizes, int n_in,
                              void* d_out, int out_size, void* d_ws, size_t ws_size,
                              hipStream_t stream) {
    const float* u    = (const float*)d_in[0];
    const float* w_re = (const float*)d_in[1];
    const float* w_im = (const float*)d_in[2];
    const float* C_re = (const float*)d_in[3];
    const float* C_im = (const float*)d_in[4];
    const float* Dp   = (const float*)d_in[5];
    const float* dt   = (const float*)d_in[6];
    float* out = (float*)d_out;
    float* Wf  = (float*)d_ws;
    short* Wb  = (short*)d_ws;

    int pre_threads = cH * cN + NB;
    hipLaunchKernelGGL(k_precomp, dim3((pre_threads + 255) / 256), dim3(256), 0, stream,
                       w_re, w_im, C_re, C_im, dt, Wf);
    hipLaunchKernelGGL(k_kf,    dim3(cH * (NB / 256)), dim3(256), 0, stream, Wf);
    hipLaunchKernelGGL(k_tab1,  dim3((NB * 2048) / 256), dim3(256), 0, stream, Wb);
    hipLaunchKernelGGL(k_tab2,  dim3((2048 * 2048) / 256), dim3(256), 0, stream, Wb);
    hipLaunchKernelGGL(k_trans, dim3(cL / 64, cH / 64, cB), dim3(256), 0, stream, u, Wb);
    hipLaunchKernelGGL(k_fwd,   dim3(NB / 128, BH / 128), dim3(256), 0, stream, Wf, Wb);
    hipLaunchKernelGGL(k_inv,   dim3(cL / 128, BH / 128), dim3(256), 0, stream, u, Dp, Wb, out);
}

// Round 3
// 278.534 us; speedup vs baseline: 12.8522x; 1.2708x over previous
//
#include <hip/hip_runtime.h>
#include <hip/hip_bf16.h>
#include <math.h>

// S4DConv via MFMA: B=8, L=2048, H=512, N=64, CH=1
//   k[h,t]    = 2 Re(sum_n Cs z^t)  (VALU recurrence, bf16)          [k_kgen]
//   K_f[h,j]  = GEMM: k x {T1c,T1s} (dual), fp32 out, scale folded   [k_kf2]
//   U^T[bh,j] = GEMM: Au x {T1c,T1s} (dual); epilogue x K_f -> Ys    [k_fwd]
//   y^T[bh,t] = GEMM: Ys x T2 (K=4096); epilogue + D*u -> out        [k_inv]

namespace {
constexpr int cB = 8;
constexpr int cL = 2048;
constexpr int cH = 512;
constexpr int cN = 64;
constexpr int M1 = 4095;
constexpr int M2 = 4096;
constexpr int NB = 2048;
constexpr int BH = cB * cH;   // 4096

// float-offset regions in ws
constexpr size_t WS_MODES = 0;                        // [H][N][6]: Cs_re,Cs_im,z_re,z_im,ar,ai
constexpr size_t WS_JTAB  = (size_t)cH * cN * 6;      // (unused, kept for layout)
constexpr size_t WS_KF    = WS_JTAB + (size_t)NB * 4; // [H][NB][2] (scale folded)
// short-offset regions (ws viewed as short*)
constexpr size_t S_BF  = 2 * (WS_KF + (size_t)cH * NB * 2);
constexpr size_t S_T1C = S_BF;                          // [NB][2048]
constexpr size_t S_T1S = S_T1C + (size_t)NB * 2048;     // [NB][2048]
constexpr size_t S_T2  = S_T1S + (size_t)NB * 2048;     // [2048][4096]
constexpr size_t S_AU  = S_T2  + (size_t)2048 * 4096;   // [BH][2048]
constexpr size_t S_YS  = S_AU  + (size_t)BH * 2048;     // [BH][4096]; rows 0..255 reused as k[H][2048] before k_fwd
constexpr size_t S_K   = S_YS;                          // k[H][2048] bf16 (consumed by k_kf2 before k_fwd overwrites)
}

typedef __attribute__((ext_vector_type(8))) short short8;
typedef __attribute__((ext_vector_type(4))) float f32x4;

static __device__ inline short f2bf(float x) {
    __hip_bfloat16 h = __float2bfloat16(x);
    return *reinterpret_cast<short*>(&h);
}

static __device__ __forceinline__ void load_lds16(const short* g, short* l) {
    __builtin_amdgcn_global_load_lds(
        (const __attribute__((address_space(1))) void*)g,
        (__attribute__((address_space(3))) void*)l, 16, 0, 0);
}

__global__ __launch_bounds__(256) void k_precomp(
    const float* __restrict__ w_re, const float* __restrict__ w_im,
    const float* __restrict__ C_re, const float* __restrict__ C_im,
    const float* __restrict__ dt, float* __restrict__ W)
{
    int idx = blockIdx.x * 256 + threadIdx.x;
    if (idx >= cH * cN) return;
    int h = idx / cN;
    double dtv = dt[h];
    double wr = w_re[idx], wi = w_im[idx];
    double ar = wr * dtv, ai = wi * dtv;
    double er = exp(ar);
    double zs, zc; sincos(ai, &zs, &zc);
    double zr = er * zc, zi = er * zs;
    double nr = zr - 1.0, ni = zi;
    double inv = 1.0 / (wr * wr + wi * wi);
    double gr = (nr * wr + ni * wi) * inv;
    double gi = (ni * wr - nr * wi) * inv;
    double cr = C_re[idx], ci = C_im[idx];
    double csr = cr * gr - ci * gi, csi = cr * gi + ci * gr;
    float* m = W + WS_MODES + (size_t)idx * 6;
    m[0] = (float)csr; m[1] = (float)csi;
    m[2] = (float)zr;  m[3] = (float)zi;
    m[4] = (float)ar;  m[5] = (float)ai;
}

// T1c[j][t]=cos(2pi*jt/4095), T1s[j][t]=sin(2pi*jt/4095)
__global__ __launch_bounds__(256) void k_tab1(short* __restrict__ Wb)
{
    int g = blockIdx.x * 256 + threadIdx.x;
    int j = g >> 11, t = g & 2047;
    int p = (j * t) % M1;
    float s, c;
    sincosf((6.283185307179586f / (float)M1) * (float)p, &s, &c);
    Wb[S_T1C + (size_t)g] = f2bf(c);
    Wb[S_T1S + (size_t)g] = f2bf(s);
}

// T2[t][j]=cos(2pi*tj/4096), T2[t][2048+j]=sin(2pi*tj/4096)
__global__ __launch_bounds__(256) void k_tab2(short* __restrict__ Wb)
{
    int g = blockIdx.x * 256 + threadIdx.x;
    int t = g >> 11, j = g & 2047;
    int p = (t * j) & (M2 - 1);
    float s, c;
    sincosf((6.283185307179586f / (float)M2) * (float)p, &s, &c);
    Wb[S_T2 + (size_t)t * 4096 + j]        = f2bf(c);
    Wb[S_T2 + (size_t)t * 4096 + 2048 + j] = f2bf(s);
}

// Au[b*512+h][t] = bf16(u[b][t][h])
__global__ __launch_bounds__(256) void k_trans(const float* __restrict__ u,
                                               short* __restrict__ Wb)
{
    __shared__ float tile[64][65];
    int t0 = blockIdx.x * 64;
    int h0 = blockIdx.y * 64;
    int b  = blockIdx.z;
    int cx = threadIdx.x & 63, r0 = threadIdx.x >> 6;
#pragma unroll
    for (int i = 0; i < 16; ++i) {
        int row = r0 + i * 4;
        tile[row][cx] = u[((size_t)b * cL + t0 + row) * cH + h0 + cx];
    }
    __syncthreads();
    short* Au = Wb + S_AU;
#pragma unroll
    for (int i = 0; i < 16; ++i) {
        int hrow = r0 + i * 4;
        Au[(size_t)(b * cH + h0 + hrow) * 2048 + t0 + cx] = f2bf(tile[cx][hrow]);
    }
}

// k[h][t] = 2 Re(sum_n Cs z^t): block per h, thread owns 8 consecutive t
__global__ __launch_bounds__(256) void k_kgen(const float* __restrict__ Wf,
                                              short* __restrict__ Wb)
{
    __shared__ float md[cN * 6];
    int h = blockIdx.x, tid = threadIdx.x;
    for (int i = tid; i < cN * 6; i += 256)
        md[i] = Wf[WS_MODES + (size_t)h * cN * 6 + i];
    __syncthreads();
    int t0 = tid * 8;
    float acc[8] = {0.f, 0.f, 0.f, 0.f, 0.f, 0.f, 0.f, 0.f};
    for (int n = 0; n < cN; ++n) {
        float csr = md[n*6+0], csi = md[n*6+1];
        float zr  = md[n*6+2], zi  = md[n*6+3];
        float ar  = md[n*6+4], ai  = md[n*6+5];
        float mag = expf(ar * (float)t0);
        double ph = fmod((double)ai * (double)t0, 6.283185307179586);
        float s, c; sincosf((float)ph, &s, &c);
        float pr = mag * c, pi = mag * s;
#pragma unroll
        for (int i = 0; i < 8; ++i) {
            acc[i] += csr * pr - csi * pi;
            float tr = pr * zr - pi * zi;
            pi = pr * zi + pi * zr;
            pr = tr;
        }
    }
    short8 v;
#pragma unroll
    for (int i = 0; i < 8; ++i) v[i] = f2bf(2.f * acc[i]);
    *reinterpret_cast<short8*>(&Wb[S_K + (size_t)h * 2048 + t0]) = v;
}

// K_f GEMM: [h=512]x[j=2048], K=2048, dual cos/sin; fp32 out with scale folded
__global__ __launch_bounds__(256) void k_kf2(float* __restrict__ Wf,
                                             const short* __restrict__ Wb)
{
    __shared__ short As[64][40], Bc[64][40], Bs[64][40];
    const short* K   = Wb + S_K;
    const short* T1c = Wb + S_T1C;
    const short* T1s = Wb + S_T1S;
    const int tid = threadIdx.x;
    const int m0 = blockIdx.y * 64, n0 = blockIdx.x * 64;
    const int wave = tid >> 6, lane = tid & 63;
    const int wr = wave >> 1, wc = wave & 1;
    const int lm = lane & 15, lk = lane >> 4;
    const int r0 = tid >> 2, cb = tid & 3;

    f32x4 accC[2][2] = {}, accS[2][2] = {};

    for (int k0 = 0; k0 < 2048; k0 += 32) {
        __syncthreads();
        *(short8*)&As[r0][cb*8] = *(const short8*)&K  [(size_t)(m0+r0)*2048 + k0 + cb*8];
        *(short8*)&Bc[r0][cb*8] = *(const short8*)&T1c[(size_t)(n0+r0)*2048 + k0 + cb*8];
        *(short8*)&Bs[r0][cb*8] = *(const short8*)&T1s[(size_t)(n0+r0)*2048 + k0 + cb*8];
        __syncthreads();
        short8 a[2];
#pragma unroll
        for (int mi = 0; mi < 2; ++mi)
            a[mi] = *(const short8*)&As[wr*32 + mi*16 + lm][lk*8];
#pragma unroll
        for (int ni = 0; ni < 2; ++ni) {
            short8 bc = *(const short8*)&Bc[wc*32 + ni*16 + lm][lk*8];
            short8 bs = *(const short8*)&Bs[wc*32 + ni*16 + lm][lk*8];
#pragma unroll
            for (int mi = 0; mi < 2; ++mi) {
                accC[mi][ni] = __builtin_amdgcn_mfma_f32_16x16x32_bf16(a[mi], bc, accC[mi][ni], 0, 0, 0);
                accS[mi][ni] = __builtin_amdgcn_mfma_f32_16x16x32_bf16(a[mi], bs, accS[mi][ni], 0, 0, 0);
            }
        }
    }
#pragma unroll
    for (int mi = 0; mi < 2; ++mi)
#pragma unroll
    for (int ni = 0; ni < 2; ++ni)
#pragma unroll
    for (int r = 0; r < 4; ++r) {
        int h = m0 + wr*32 + mi*16 + lk*4 + r;
        int j = n0 + wc*32 + ni*16 + lm;
        float scale = (j == 0 ? 1.0f : 2.0f) / (float)M2;
        float* o = Wf + WS_KF + ((size_t)h * NB + j) * 2;
        o[0] =  accC[mi][ni][r] * scale;
        o[1] = -accS[mi][ni][r] * scale;
    }
}

// forward dual GEMM: tile 128(bh) x 64(j), K=2048; global_load_lds staging
__global__ __launch_bounds__(256, 2) void k_fwd(const float* __restrict__ Wf,
                                                short* __restrict__ Wb)
{
    __shared__ __align__(16) short As[128][32];
    __shared__ __align__(16) short Bc[64][32];
    __shared__ __align__(16) short Bs[64][32];
    const short* Au  = Wb + S_AU;
    const short* T1c = Wb + S_T1C;
    const short* T1s = Wb + S_T1S;
    short* Ys = Wb + S_YS;
    const int tid = threadIdx.x;
    const int m0 = blockIdx.y * 128, n0 = blockIdx.x * 64;
    const int wave = tid >> 6, lane = tid & 63;
    const int wr = wave >> 1, wc = wave & 1;
    const int lm = lane & 15, lk = lane >> 4;
    const int srow = lane >> 2, scol = (lane & 3) * 8;

    f32x4 accC[4][2] = {}, accS[4][2] = {};

    for (int k0 = 0; k0 < 2048; k0 += 32) {
        __syncthreads();
        {
            int c0 = wave * 2;
            load_lds16(&Au [(size_t)(m0 + c0*16      + srow)*2048 + k0 + scol], &As[c0*16][0]);
            load_lds16(&Au [(size_t)(m0 + c0*16 + 16 + srow)*2048 + k0 + scol], &As[c0*16+16][0]);
            load_lds16(&T1c[(size_t)(n0 + wave*16    + srow)*2048 + k0 + scol], &Bc[wave*16][0]);
            load_lds16(&T1s[(size_t)(n0 + wave*16    + srow)*2048 + k0 + scol], &Bs[wave*16][0]);
        }
        __syncthreads();
        short8 a[4];
#pragma unroll
        for (int mi = 0; mi < 4; ++mi)
            a[mi] = *(const short8*)&As[wr*64 + mi*16 + lm][lk*8];
#pragma unroll
        for (int ni = 0; ni < 2; ++ni) {
            short8 bc = *(const short8*)&Bc[wc*32 + ni*16 + lm][lk*8];
            short8 bs = *(const short8*)&Bs[wc*32 + ni*16 + lm][lk*8];
#pragma unroll
            for (int mi = 0; mi < 4; ++mi) {
                accC[mi][ni] = __builtin_amdgcn_mfma_f32_16x16x32_bf16(a[mi], bc, accC[mi][ni], 0, 0, 0);
                accS[mi][ni] = __builtin_amdgcn_mfma_f32_16x16x32_bf16(a[mi], bs, accS[mi][ni], 0, 0, 0);
            }
        }
    }

    const float* KF = Wf + WS_KF;
#pragma unroll
    for (int mi = 0; mi < 4; ++mi)
#pragma unroll
    for (int ni = 0; ni < 2; ++ni)
#pragma unroll
    for (int r = 0; r < 4; ++r) {
        int bh = m0 + wr*64 + mi*16 + lk*4 + r;
        int j  = n0 + wc*32 + ni*16 + lm;
        int h  = bh & (cH - 1);
        float2 kf = *(const float2*)&KF[((size_t)h * NB + j) * 2];
        float ur = accC[mi][ni][r], ui = -accS[mi][ni][r];
        float ysr = kf.x * ur - kf.y * ui;
        float ysi = kf.x * ui + kf.y * ur;
        Ys[(size_t)bh * 4096 + j]        = f2bf(ysr);
        Ys[(size_t)bh * 4096 + 2048 + j] = f2bf(-ysi);
    }
}

// inverse GEMM: tile 128(bh) x 128(t), K=4096; global_load_lds staging
__global__ __launch_bounds__(256, 2) void k_inv(const float* __restrict__ u,
                                                const float* __restrict__ Dp,
                                                const short* __restrict__ Wb,
                                                float* __restrict__ out)
{
    __shared__ __align__(16) short As[128][32];
    __shared__ __align__(16) short Bt[128][32];
    const short* Ys = Wb + S_YS;
    const short* T2 = Wb + S_T2;
    const int tid = threadIdx.x;
    const int m0 = blockIdx.y * 128, n0 = blockIdx.x * 128;
    const int wave = tid >> 6, lane = tid & 63;
    const int wr = wave >> 1, wc = wave & 1;
    const int lm = lane & 15, lk = lane >> 4;
    const int srow = lane >> 2, scol = (lane & 3) * 8;

    f32x4 acc[4][4] = {};

    for (int k0 = 0; k0 < 4096; k0 += 32) {
        __syncthreads();
        {
            int c0 = wave * 2;
            load_lds16(&Ys[(size_t)(m0 + c0*16      + srow)*4096 + k0 + scol], &As[c0*16][0]);
            load_lds16(&Ys[(size_t)(m0 + c0*16 + 16 + srow)*4096 + k0 + scol], &As[c0*16+16][0]);
            load_lds16(&T2[(size_t)(n0 + c0*16      + srow)*4096 + k0 + scol], &Bt[c0*16][0]);
            load_lds16(&T2[(size_t)(n0 + c0*16 + 16 + srow)*4096 + k0 + scol], &Bt[c0*16+16][0]);
        }
        __syncthreads();
        short8 a[4];
#pragma unroll
        for (int mi = 0; mi < 4; ++mi)
            a[mi] = *(const short8*)&As[wr*64 + mi*16 + lm][lk*8];
#pragma unroll
        for (int ni = 0; ni < 4; ++ni) {
            short8 b = *(const short8*)&Bt[wc*64 + ni*16 + lm][lk*8];
#pragma unroll
            for (int mi = 0; mi < 4; ++mi)
                acc[mi][ni] = __builtin_amdgcn_mfma_f32_16x16x32_bf16(a[mi], b, acc[mi][ni], 0, 0, 0);
        }
    }

#pragma unroll
    for (int mi = 0; mi < 4; ++mi)
#pragma unroll
    for (int ni = 0; ni < 4; ++ni)
#pragma unroll
    for (int r = 0; r < 4; ++r) {
        int bh = m0 + wr*64 + mi*16 + lk*4 + r;
        int t  = n0 + wc*64 + ni*16 + lm;
        int b  = bh >> 9, h = bh & (cH - 1);
        size_t idx = ((size_t)b * cL + t) * cH + h;
        out[idx] = acc[mi][ni][r] + Dp[h] * u[idx];
    }
}

extern "C" void kernel_launch(void* const* d_in, const int* in_sizes, int n_in,
                              void* d_out, int out_size, void* d_ws, size_t ws_size,
                              hipStream_t stream) {
    const float* u    = (const float*)d_in[0];
    const float* w_re = (const float*)d_in[1];
    const float* w_im = (const float*)d_in[2];
    const float* C_re = (const float*)d_in[3];
    const float* C_im = (const float*)d_in[4];
    const float* Dp   = (const float*)d_in[5];
    const float* dt   = (const float*)d_in[6];
    float* out = (float*)d_out;
    float* Wf  = (float*)d_ws;
    short* Wb  = (short*)d_ws;

    hipLaunchKernelGGL(k_precomp, dim3((cH * cN + 255) / 256), dim3(256), 0, stream,
                       w_re, w_im, C_re, C_im, dt, Wf);
    hipLaunchKernelGGL(k_tab1,  dim3((NB * 2048) / 256), dim3(256), 0, stream, Wb);
    hipLaunchKernelGGL(k_tab2,  dim3((2048 * 2048) / 256), dim3(256), 0, stream, Wb);
    hipLaunchKernelGGL(k_trans, dim3(cL / 64, cH / 64, cB), dim3(256), 0, stream, u, Wb);
    hipLaunchKernelGGL(k_kgen,  dim3(cH), dim3(256), 0, stream, Wf, Wb);
    hipLaunchKernelGGL(k_kf2,   dim3(NB / 64, cH / 64), dim3(256), 0, stream, Wf, Wb);
    hipLaunchKernelGGL(k_fwd,   dim3(NB / 64, BH / 128), dim3(256), 0, stream, Wf, Wb);
    hipLaunchKernelGGL(k_inv,   dim3(cL / 128, BH / 128), dim3(256), 0, stream, u, Dp, Wb, out);
}